// Round 1
// baseline (754.912 us; speedup 1.0000x reference)
//
#include <hip/hip_runtime.h>

// -------------------------------------------------------------------------
// Problem: N=1e6 nodes, D=128 feat, G=16384 graphs (batch sorted).
// out = relu(meanpool_w(x) @ W1 + b1) @ W2 + b2, where per-node weight
// w = imp / (10 * segmax(imp)) + 0.9 and pool is a per-graph mean.
// Memory-bound on the single read of x (512 MB). fp32 throughout.
// -------------------------------------------------------------------------

// Kernel 1: segment start offsets from sorted batch. start has G+1 entries.
__global__ void bounds_kernel(const int* __restrict__ batch,
                              int* __restrict__ start, int N, int G) {
    int i = blockIdx.x * blockDim.x + threadIdx.x;
    if (i >= N) return;
    int b = batch[i];
    int prev = (i == 0) ? -1 : batch[i - 1];
    for (int g = prev + 1; g <= b; ++g) start[g] = i;   // total writes = G+1
    if (i == N - 1) {
        for (int g = b + 1; g <= G; ++g) start[g] = N;
    }
}

// Kernel 2: fused segment-max + weighted mean pool. One block per graph,
// 128 threads: thread t owns feature column t. Graph rows are contiguous
// (batch sorted) -> fully coalesced streaming of x.
__global__ __launch_bounds__(128) void pool_kernel(
        const float* __restrict__ x, const float* __restrict__ imp,
        const int* __restrict__ start, float* __restrict__ pooled) {
    const int g = blockIdx.x;
    const int t = threadIdx.x;
    const int s = start[g];
    const int e = start[g + 1];
    const int n = e - s;

    // Phase 1: segment max of imp[s..e)
    __shared__ float smax[2];
    float m = -1e30f;
    for (int i = s + t; i < e; i += 128) m = fmaxf(m, imp[i]);
    #pragma unroll
    for (int off = 32; off > 0; off >>= 1)
        m = fmaxf(m, __shfl_down(m, off, 64));
    if ((t & 63) == 0) smax[t >> 6] = m;
    __syncthreads();
    const float gmax = fmaxf(smax[0], smax[1]);
    const float inv = 0.1f / gmax;       // 1 / (gmax * 10)

    // Phase 2: acc over rows; weight broadcast-loaded from L1.
    float acc = 0.0f;
    const float* xp = x + (long long)s * 128 + t;
    for (int i = s; i < e; ++i) {
        const float w = imp[i] * inv + 0.9f;
        acc += xp[0] * w;
        xp += 128;
    }
    const float cnt = (n > 0) ? (float)n : 1.0f;
    pooled[(long long)g * 128 + t] = acc / cnt;
}

// Kernels 3/4: out[r][c] = act( sum_k P[r][k] * W[k][c] + bias[c] ).
// 32 rows per block, 256 threads, 4x4 register tile per thread.
// W streamed from global (L2-resident, 64 KB). Safe in-place (P == out):
// each block reads only rows it writes, and __syncthreads() separates
// all reads from all writes within the block.
__global__ __launch_bounds__(256) void gemm128_kernel(
        const float* __restrict__ P, const float* __restrict__ W,
        const float* __restrict__ bias, float* __restrict__ out,
        int do_relu) {
    const int t = threadIdx.x;
    const int cg = (t & 31) * 4;        // column group: 0..124
    const int rg = (t >> 5) * 4;        // row group within tile: 0..28
    const long long row0 = (long long)blockIdx.x * 32 + rg;

    const float* p0 = P + row0 * 128;
    const float* p1 = p0 + 128;
    const float* p2 = p0 + 256;
    const float* p3 = p0 + 384;

    float acc[4][4] = {};
    #pragma unroll 4
    for (int k = 0; k < 128; ++k) {
        const float4 wv = *(const float4*)(W + k * 128 + cg);
        const float a0 = p0[k], a1 = p1[k], a2 = p2[k], a3 = p3[k];
        acc[0][0] += a0 * wv.x; acc[0][1] += a0 * wv.y;
        acc[0][2] += a0 * wv.z; acc[0][3] += a0 * wv.w;
        acc[1][0] += a1 * wv.x; acc[1][1] += a1 * wv.y;
        acc[1][2] += a1 * wv.z; acc[1][3] += a1 * wv.w;
        acc[2][0] += a2 * wv.x; acc[2][1] += a2 * wv.y;
        acc[2][2] += a2 * wv.z; acc[2][3] += a2 * wv.w;
        acc[3][0] += a3 * wv.x; acc[3][1] += a3 * wv.y;
        acc[3][2] += a3 * wv.z; acc[3][3] += a3 * wv.w;
    }

    __syncthreads();   // all reads of P done before any write (in-place safe)

    const float4 bv = *(const float4*)(bias + cg);
    #pragma unroll
    for (int j = 0; j < 4; ++j) {
        float4 o;
        o.x = acc[j][0] + bv.x;
        o.y = acc[j][1] + bv.y;
        o.z = acc[j][2] + bv.z;
        o.w = acc[j][3] + bv.w;
        if (do_relu) {
            o.x = fmaxf(o.x, 0.0f); o.y = fmaxf(o.y, 0.0f);
            o.z = fmaxf(o.z, 0.0f); o.w = fmaxf(o.w, 0.0f);
        }
        *(float4*)(out + (row0 + j) * 128 + cg) = o;
    }
}

extern "C" void kernel_launch(void* const* d_in, const int* in_sizes, int n_in,
                              void* d_out, int out_size, void* d_ws, size_t ws_size,
                              hipStream_t stream) {
    const float* x        = (const float*)d_in[0];
    const float* node_imp = (const float*)d_in[1];
    const int*   batch    = (const int*)d_in[2];
    const float* W1       = (const float*)d_in[3];
    const float* b1       = (const float*)d_in[4];
    const float* W2       = (const float*)d_in[5];
    const float* b2       = (const float*)d_in[6];

    const int N = in_sizes[1];          // node_imp has N elements
    const int D = in_sizes[4];          // b1 has D elements (=128)
    const int G = out_size / D;         // output is (G, D)

    float* out = (float*)d_out;

    // Workspace layout: start[G+1] ints, then pooled[G*D] floats (256B align)
    int* start = (int*)d_ws;
    size_t off = (((size_t)(G + 1) * sizeof(int)) + 255) & ~(size_t)255;
    float* pooled = (float*)((char*)d_ws + off);

    bounds_kernel<<<(N + 255) / 256, 256, 0, stream>>>(batch, start, N, G);
    pool_kernel<<<G, 128, 0, stream>>>(x, node_imp, start, pooled);
    gemm128_kernel<<<G / 32, 256, 0, stream>>>(pooled, W1, b1, out, 1);
    gemm128_kernel<<<G / 32, 256, 0, stream>>>(out, W2, b2, out, 0);
}

// Round 2
// 702.440 us; speedup vs baseline: 1.0747x; 1.0747x over previous
//
#include <hip/hip_runtime.h>

// -------------------------------------------------------------------------
// N=1e6 nodes, D=128, G=16384 graphs (batch sorted).
// out = relu(meanpool_w(x) @ W1 + b1) @ W2 + b2,
//   w = imp / (10 * segmax(imp)) + 0.9, mean pool per graph.
// Memory-bound on the single 512 MB read of x. fp32 throughout.
// R2: pool vectorized to float4 (16 B/lane), GEMMs fused into one kernel
//     with LDS-staged tiles.
// -------------------------------------------------------------------------

// Kernel 1: segment start offsets from sorted batch. start has G+1 entries.
__global__ void bounds_kernel(const int* __restrict__ batch,
                              int* __restrict__ start, int N, int G) {
    int i = blockIdx.x * blockDim.x + threadIdx.x;
    if (i >= N) return;
    int b = batch[i];
    int prev = (i == 0) ? -1 : batch[i - 1];
    for (int g = prev + 1; g <= b; ++g) start[g] = i;
    if (i == N - 1) {
        for (int g = b + 1; g <= G; ++g) start[g] = N;
    }
}

// Kernel 2: fused segment-max + weighted mean pool. One block (256 thr) per
// graph. Thread t: row-group rg = t>>5 (8 rows in flight), col-group
// cg = t&31 (float4 -> 4 cols). One wave's load = 2 contiguous rows (1 KB).
__global__ __launch_bounds__(256) void pool_kernel(
        const float* __restrict__ x, const float* __restrict__ imp,
        const int* __restrict__ start, float* __restrict__ pooled) {
    const int g = blockIdx.x;
    const int t = threadIdx.x;
    const int s = start[g];
    const int e = start[g + 1];
    const int n = e - s;

    // ---- Phase 1: segment max of imp[s..e) ----
    __shared__ float smax[4];
    float m = -1e30f;
    for (int i = s + t; i < e; i += 256) m = fmaxf(m, imp[i]);
    #pragma unroll
    for (int off = 32; off > 0; off >>= 1)
        m = fmaxf(m, __shfl_down(m, off, 64));
    if ((t & 63) == 0) smax[t >> 6] = m;
    __syncthreads();
    const float gmax = fmaxf(fmaxf(smax[0], smax[1]), fmaxf(smax[2], smax[3]));
    const float inv = 0.1f / gmax;   // 1/(gmax*10)

    // ---- Phase 2: weighted accumulate, float4 per thread ----
    const int rg = t >> 5;          // 0..7
    const int cg = (t & 31) * 4;    // 0..124
    float ax = 0.f, ay = 0.f, az = 0.f, aw = 0.f;
    for (int i = s + rg; i < e; i += 8) {
        const float w = imp[i] * inv + 0.9f;
        const float4 xv = *(const float4*)(x + (long long)i * 128 + cg);
        ax += xv.x * w; ay += xv.y * w; az += xv.z * w; aw += xv.w * w;
    }

    // ---- Reduce across the 8 row-groups ----
    // Within a wave: rg pairs (0,1) and (2,3)... combine via shfl_down 32.
    ax += __shfl_down(ax, 32, 64);
    ay += __shfl_down(ay, 32, 64);
    az += __shfl_down(az, 32, 64);
    aw += __shfl_down(aw, 32, 64);
    __shared__ float red[4][32][4];
    const int wave = t >> 6, lane = t & 63;
    if (lane < 32) {
        red[wave][lane][0] = ax; red[wave][lane][1] = ay;
        red[wave][lane][2] = az; red[wave][lane][3] = aw;
    }
    __syncthreads();
    if (t < 32) {
        const float rs = 1.0f / ((n > 0) ? (float)n : 1.0f);
        float4 o;
        o.x = (red[0][t][0] + red[1][t][0] + red[2][t][0] + red[3][t][0]) * rs;
        o.y = (red[0][t][1] + red[1][t][1] + red[2][t][1] + red[3][t][1]) * rs;
        o.z = (red[0][t][2] + red[1][t][2] + red[2][t][2] + red[3][t][2]) * rs;
        o.w = (red[0][t][3] + red[1][t][3] + red[2][t][3] + red[3][t][3]) * rs;
        *(float4*)(pooled + (long long)g * 128 + t * 4) = o;
    }
}

// Kernel 3: fused 2-layer MLP. One block = 32 rows. P tile staged in LDS
// (stride 132 floats to de-alias banks), h round-trips through the same
// buffer. W1/W2 streamed from global (L1/L2-resident, 64 KB each).
__global__ __launch_bounds__(256) void mlp_kernel(
        const float* __restrict__ P,
        const float* __restrict__ W1, const float* __restrict__ b1,
        const float* __restrict__ W2, const float* __restrict__ b2,
        float* __restrict__ out) {
    __shared__ float T[32 * 132];
    const int t = threadIdx.x;
    const int cg = (t & 31) * 4;          // cols 0..124
    const int rg = (t >> 5) * 4;          // rows 0..28
    const long long base = (long long)blockIdx.x * 32;

    // Stage P tile: 32 rows x 128 cols = 1024 float4
    const float4* Pg = (const float4*)(P + base * 128);
    #pragma unroll
    for (int idx = t; idx < 1024; idx += 256) {
        const int r = idx >> 5, c = idx & 31;
        *(float4*)&T[r * 132 + c * 4] = Pg[idx];
    }
    __syncthreads();

    // GEMM1: h = relu(P @ W1 + b1)
    float acc[4][4] = {};
    #pragma unroll 4
    for (int k = 0; k < 128; ++k) {
        const float4 wv = *(const float4*)(W1 + k * 128 + cg);
        const float a0 = T[(rg + 0) * 132 + k];
        const float a1 = T[(rg + 1) * 132 + k];
        const float a2 = T[(rg + 2) * 132 + k];
        const float a3 = T[(rg + 3) * 132 + k];
        acc[0][0] += a0 * wv.x; acc[0][1] += a0 * wv.y;
        acc[0][2] += a0 * wv.z; acc[0][3] += a0 * wv.w;
        acc[1][0] += a1 * wv.x; acc[1][1] += a1 * wv.y;
        acc[1][2] += a1 * wv.z; acc[1][3] += a1 * wv.w;
        acc[2][0] += a2 * wv.x; acc[2][1] += a2 * wv.y;
        acc[2][2] += a2 * wv.z; acc[2][3] += a2 * wv.w;
        acc[3][0] += a3 * wv.x; acc[3][1] += a3 * wv.y;
        acc[3][2] += a3 * wv.z; acc[3][3] += a3 * wv.w;
    }
    __syncthreads();   // all T reads done before h overwrite

    {
        const float4 bv = *(const float4*)(b1 + cg);
        #pragma unroll
        for (int j = 0; j < 4; ++j) {
            float4 o;
            o.x = fmaxf(acc[j][0] + bv.x, 0.f);
            o.y = fmaxf(acc[j][1] + bv.y, 0.f);
            o.z = fmaxf(acc[j][2] + bv.z, 0.f);
            o.w = fmaxf(acc[j][3] + bv.w, 0.f);
            *(float4*)&T[(rg + j) * 132 + cg] = o;
        }
    }
    __syncthreads();

    // GEMM2: out = h @ W2 + b2
    float acc2[4][4] = {};
    #pragma unroll 4
    for (int k = 0; k < 128; ++k) {
        const float4 wv = *(const float4*)(W2 + k * 128 + cg);
        const float a0 = T[(rg + 0) * 132 + k];
        const float a1 = T[(rg + 1) * 132 + k];
        const float a2 = T[(rg + 2) * 132 + k];
        const float a3 = T[(rg + 3) * 132 + k];
        acc2[0][0] += a0 * wv.x; acc2[0][1] += a0 * wv.y;
        acc2[0][2] += a0 * wv.z; acc2[0][3] += a0 * wv.w;
        acc2[1][0] += a1 * wv.x; acc2[1][1] += a1 * wv.y;
        acc2[1][2] += a1 * wv.z; acc2[1][3] += a1 * wv.w;
        acc2[2][0] += a2 * wv.x; acc2[2][1] += a2 * wv.y;
        acc2[2][2] += a2 * wv.z; acc2[2][3] += a2 * wv.w;
        acc2[3][0] += a3 * wv.x; acc2[3][1] += a3 * wv.y;
        acc2[3][2] += a3 * wv.z; acc2[3][3] += a3 * wv.w;
    }

    const float4 bv2 = *(const float4*)(b2 + cg);
    #pragma unroll
    for (int j = 0; j < 4; ++j) {
        float4 o;
        o.x = acc2[j][0] + bv2.x;
        o.y = acc2[j][1] + bv2.y;
        o.z = acc2[j][2] + bv2.z;
        o.w = acc2[j][3] + bv2.w;
        *(float4*)(out + (base + rg + j) * 128 + cg) = o;
    }
}

extern "C" void kernel_launch(void* const* d_in, const int* in_sizes, int n_in,
                              void* d_out, int out_size, void* d_ws, size_t ws_size,
                              hipStream_t stream) {
    const float* x        = (const float*)d_in[0];
    const float* node_imp = (const float*)d_in[1];
    const int*   batch    = (const int*)d_in[2];
    const float* W1       = (const float*)d_in[3];
    const float* b1       = (const float*)d_in[4];
    const float* W2       = (const float*)d_in[5];
    const float* b2       = (const float*)d_in[6];

    const int N = in_sizes[1];
    const int D = in_sizes[4];
    const int G = out_size / D;

    float* out = (float*)d_out;

    int* start = (int*)d_ws;
    size_t off = (((size_t)(G + 1) * sizeof(int)) + 255) & ~(size_t)255;
    float* pooled = (float*)((char*)d_ws + off);

    bounds_kernel<<<(N + 255) / 256, 256, 0, stream>>>(batch, start, N, G);
    pool_kernel<<<G, 256, 0, stream>>>(x, node_imp, start, pooled);
    mlp_kernel<<<G / 32, 256, 0, stream>>>(pooled, W1, b1, W2, b2, out);
}

// Round 3
// 657.250 us; speedup vs baseline: 1.1486x; 1.0688x over previous
//
#include <hip/hip_runtime.h>

// -------------------------------------------------------------------------
// N=1e6 nodes, D=128, G=16384 graphs (batch sorted).
// out = relu(meanpool_w(x) @ W1 + b1) @ W2 + b2,
//   w = imp / (10 * segmax(imp)) + 0.9, mean pool per graph.
// dur_us includes ~590 us fixed harness reset (2 GB ws poison + x restore).
// Addressable: pool (x-stream floor ~79 us), MLP, bounds.
// R3: MLP via bf16 MFMA (fp32 accum), nontemporal x loads in pool.
// -------------------------------------------------------------------------

typedef __attribute__((ext_vector_type(8))) short short8;
typedef __attribute__((ext_vector_type(4))) float f32x4;
typedef __attribute__((ext_vector_type(4))) float f32x4v;

static __device__ __forceinline__ unsigned short f2bf(float f) {
    unsigned int u = __builtin_bit_cast(unsigned int, f);
    unsigned int lsb = (u >> 16) & 1u;
    u += 0x7fffu + lsb;              // round-to-nearest-even
    return (unsigned short)(u >> 16);
}

// Kernel 1: segment start offsets from sorted batch. start has G+1 entries.
__global__ void bounds_kernel(const int* __restrict__ batch,
                              int* __restrict__ start, int N, int G) {
    int i = blockIdx.x * blockDim.x + threadIdx.x;
    if (i >= N) return;
    int b = batch[i];
    int prev = (i == 0) ? -1 : batch[i - 1];
    for (int g = prev + 1; g <= b; ++g) start[g] = i;
    if (i == N - 1) {
        for (int g = b + 1; g <= G; ++g) start[g] = N;
    }
}

// Kernel 1b: W (D x D fp32, row-major) -> W^T (D x D bf16, row-major).
// Tiny (128 KB); perf-irrelevant.
__global__ void prep_w_kernel(const float* __restrict__ W1,
                              const float* __restrict__ W2,
                              unsigned short* __restrict__ W1T,
                              unsigned short* __restrict__ W2T) {
    int idx = blockIdx.x * blockDim.x + threadIdx.x;   // 0..16383
    if (idx >= 128 * 128) return;
    int r = idx >> 7, c = idx & 127;
    W1T[c * 128 + r] = f2bf(W1[idx]);
    W2T[c * 128 + r] = f2bf(W2[idx]);
}

// Kernel 2: fused segment-max + weighted mean pool. One block (256 thr) per
// graph. rg = t>>5 (8 rows in flight), cg = t&31 (float4 -> 4 cols).
// x loaded nontemporal (stream-once, 512 MB).
__global__ __launch_bounds__(256) void pool_kernel(
        const float* __restrict__ x, const float* __restrict__ imp,
        const int* __restrict__ start, float* __restrict__ pooled) {
    const int g = blockIdx.x;
    const int t = threadIdx.x;
    const int s = start[g];
    const int e = start[g + 1];
    const int n = e - s;

    // ---- Phase 1: segment max of imp[s..e) ----
    __shared__ float smax[4];
    float m = -1e30f;
    for (int i = s + t; i < e; i += 256) m = fmaxf(m, imp[i]);
    #pragma unroll
    for (int off = 32; off > 0; off >>= 1)
        m = fmaxf(m, __shfl_down(m, off, 64));
    if ((t & 63) == 0) smax[t >> 6] = m;
    __syncthreads();
    const float gmax = fmaxf(fmaxf(smax[0], smax[1]), fmaxf(smax[2], smax[3]));
    const float inv = 0.1f / gmax;   // 1/(gmax*10)

    // ---- Phase 2: weighted accumulate, float4 per thread ----
    const int rg = t >> 5;
    const int cg = (t & 31) * 4;
    float ax = 0.f, ay = 0.f, az = 0.f, aw = 0.f;
    for (int i = s + rg; i < e; i += 8) {
        const float w = imp[i] * inv + 0.9f;
        const f32x4v xv = __builtin_nontemporal_load(
            (const f32x4v*)(x + (long long)i * 128 + cg));
        ax += xv.x * w; ay += xv.y * w; az += xv.z * w; aw += xv.w * w;
    }

    // ---- Reduce across the 8 row-groups ----
    ax += __shfl_down(ax, 32, 64);
    ay += __shfl_down(ay, 32, 64);
    az += __shfl_down(az, 32, 64);
    aw += __shfl_down(aw, 32, 64);
    __shared__ float red[4][32][4];
    const int wave = t >> 6, lane = t & 63;
    if (lane < 32) {
        red[wave][lane][0] = ax; red[wave][lane][1] = ay;
        red[wave][lane][2] = az; red[wave][lane][3] = aw;
    }
    __syncthreads();
    if (t < 32) {
        const float rs = 1.0f / ((n > 0) ? (float)n : 1.0f);
        float4 o;
        o.x = (red[0][t][0] + red[1][t][0] + red[2][t][0] + red[3][t][0]) * rs;
        o.y = (red[0][t][1] + red[1][t][1] + red[2][t][1] + red[3][t][1]) * rs;
        o.z = (red[0][t][2] + red[1][t][2] + red[2][t][2] + red[3][t][2]) * rs;
        o.w = (red[0][t][3] + red[1][t][3] + red[2][t][3] + red[3][t][3]) * rs;
        *(float4*)(pooled + (long long)g * 128 + t * 4) = o;
    }
}

// Kernel 3: fused 2-layer MLP via bf16 MFMA (fp32 accumulate).
// Block = 32 rows, 4 waves. Wave w: M-tile mt=w>>1, N-tiles ntb=(w&1)*4..+3.
// P staged to LDS bf16 [32][136] (+8 pad -> 2-way bank alias = free);
// h round-trips through the same buffer. B-frags = contiguous 16 B reads
// from pre-transposed bf16 W^T (L1/L2-resident).
// MFMA layouts (measured, guide §3/m89/m120):
//   A[m=lane&15][k=quad*8+j], B[k=quad*8+j][n=lane&15],
//   D: col=lane&15, row=quad*4+reg.
__global__ __launch_bounds__(256) void mlp_mfma_kernel(
        const float* __restrict__ P,
        const unsigned short* __restrict__ W1T, const float* __restrict__ b1,
        const unsigned short* __restrict__ W2T, const float* __restrict__ b2,
        float* __restrict__ out) {
    __shared__ unsigned short T[32 * 136];
    const int t = threadIdx.x;
    const int wave = t >> 6, lane = t & 63;
    const int mt = wave >> 1;             // 0..1
    const int ntb = (wave & 1) * 4;       // 0 or 4
    const int lr = lane & 15;
    const int quad = lane >> 4;           // 0..3
    const long long base = (long long)blockIdx.x * 32;

    // Stage P tile -> bf16 LDS
    for (int idx = t; idx < 1024; idx += 256) {
        const int r = idx >> 5, c4 = (idx & 31) * 4;
        const float4 v = *(const float4*)(P + (base + r) * 128 + c4);
        unsigned short* d = &T[r * 136 + c4];
        d[0] = f2bf(v.x); d[1] = f2bf(v.y);
        d[2] = f2bf(v.z); d[3] = f2bf(v.w);
    }
    __syncthreads();

    // A-frags for this wave's M-tile (reused across all 4 N-tiles)
    short8 a[4];
    #pragma unroll
    for (int ks = 0; ks < 4; ++ks)
        a[ks] = *(const short8*)&T[(mt * 16 + lr) * 136 + ks * 32 + quad * 8];

    // GEMM1: acc[nt] = P_tile @ W1 tile
    f32x4 acc[4];
    #pragma unroll
    for (int nt = 0; nt < 4; ++nt) {
        f32x4 c = {0.f, 0.f, 0.f, 0.f};
        const int col = (ntb + nt) * 16 + lr;
        #pragma unroll
        for (int ks = 0; ks < 4; ++ks) {
            const short8 b = *(const short8*)(W1T + col * 128 + ks * 32 + quad * 8);
            c = __builtin_amdgcn_mfma_f32_16x16x32_bf16(a[ks], b, c, 0, 0, 0);
        }
        acc[nt] = c;
    }
    __syncthreads();   // done reading T

    // h = relu(acc + b1) -> bf16 back into T
    #pragma unroll
    for (int nt = 0; nt < 4; ++nt) {
        const int col = (ntb + nt) * 16 + lr;
        const float bb = b1[col];
        #pragma unroll
        for (int r = 0; r < 4; ++r) {
            const int row = mt * 16 + quad * 4 + r;
            T[row * 136 + col] = f2bf(fmaxf(acc[nt][r] + bb, 0.f));
        }
    }
    __syncthreads();

    // A-frags for h
    #pragma unroll
    for (int ks = 0; ks < 4; ++ks)
        a[ks] = *(const short8*)&T[(mt * 16 + lr) * 136 + ks * 32 + quad * 8];

    // GEMM2 + bias + store
    #pragma unroll
    for (int nt = 0; nt < 4; ++nt) {
        f32x4 c = {0.f, 0.f, 0.f, 0.f};
        const int col = (ntb + nt) * 16 + lr;
        #pragma unroll
        for (int ks = 0; ks < 4; ++ks) {
            const short8 b = *(const short8*)(W2T + col * 128 + ks * 32 + quad * 8);
            c = __builtin_amdgcn_mfma_f32_16x16x32_bf16(a[ks], b, c, 0, 0, 0);
        }
        const float bb = b2[col];
        #pragma unroll
        for (int r = 0; r < 4; ++r) {
            const int row = mt * 16 + quad * 4 + r;
            out[(base + row) * 128 + col] = c[r] + bb;
        }
    }
}

extern "C" void kernel_launch(void* const* d_in, const int* in_sizes, int n_in,
                              void* d_out, int out_size, void* d_ws, size_t ws_size,
                              hipStream_t stream) {
    const float* x        = (const float*)d_in[0];
    const float* node_imp = (const float*)d_in[1];
    const int*   batch    = (const int*)d_in[2];
    const float* W1       = (const float*)d_in[3];
    const float* b1       = (const float*)d_in[4];
    const float* W2       = (const float*)d_in[5];
    const float* b2       = (const float*)d_in[6];

    const int N = in_sizes[1];
    const int D = in_sizes[4];
    const int G = out_size / D;

    float* out = (float*)d_out;

    // Workspace: start[G+1] | pooled[G*D] f32 | W1T[D*D] bf16 | W2T[D*D] bf16
    char* ws = (char*)d_ws;
    int* start = (int*)ws;
    size_t off = (((size_t)(G + 1) * sizeof(int)) + 255) & ~(size_t)255;
    float* pooled = (float*)(ws + off);
    off += ((size_t)G * D * sizeof(float) + 255) & ~(size_t)255;
    unsigned short* W1T = (unsigned short*)(ws + off);
    off += ((size_t)D * D * sizeof(unsigned short) + 255) & ~(size_t)255;
    unsigned short* W2T = (unsigned short*)(ws + off);

    bounds_kernel<<<(N + 255) / 256, 256, 0, stream>>>(batch, start, N, G);
    prep_w_kernel<<<(D * D + 255) / 256, 256, 0, stream>>>(W1, W2, W1T, W2T);
    pool_kernel<<<G, 256, 0, stream>>>(x, node_imp, start, pooled);
    mlp_mfma_kernel<<<G / 32, 256, 0, stream>>>(pooled, W1T, b1, W2T, b2, out);
}